// Round 1
// baseline (869.945 us; speedup 1.0000x reference)
//
#include <hip/hip_runtime.h>
#include <cstddef>

namespace {
constexpr int Bb   = 2;
constexpr int Tt   = 4;
constexpr int Hh   = 44;
constexpr int Ww   = 44;
constexpr int Cc   = 384;
constexpr int NH   = 12;
constexpr int HD   = 32;
constexpr int NWIN = 25;      // 5x5 windows per batch
constexpr int NT   = 400;     // tokens per window = 4*10*10
constexpr int NPOS = Hh * Ww; // 1936
constexpr float SCALE = 0.17677669529663687f; // 1/sqrt(32)
constexpr size_t QSZ = (size_t)Bb * NWIN * NH * NT * HD; // 7,680,000 floats
}

// ---------------------------------------------------------------------------
// Kernel 1: fused window-gather + QKV GEMM.
// Per window: (400 x 384) @ (384 x 1152)^T  -> scattered to Q/K/V windowed
// layout [b*25+win][head][m][hd]. Padded tokens produce zero rows (they must
// exist: zero K rows contribute exp(0) to the softmax denominator).
// 64x64 tile, 4x4 per thread, LDS tiles stored [k][m] (stride 68, conflict-free
// b128 compute reads).
// ---------------------------------------------------------------------------
__global__ __launch_bounds__(256) void qkv_kernel(
    const float* __restrict__ x, const float* __restrict__ qw,
    float* __restrict__ qo, float* __restrict__ ko, float* __restrict__ vo) {
  __shared__ float As[32][68];
  __shared__ float Bs[32][68];

  const int ntile = blockIdx.x;  // 0..17  (1152/64)
  const int mtile = blockIdx.y;  // 0..6   (ceil(400/64))
  const int bw    = blockIdx.z;  // 0..49
  const int b = bw / NWIN, win = bw % NWIN;
  const int hi = win / 5, wi = win % 5;

  const int tid = threadIdx.x;
  const int tx = tid & 15, ty = tid >> 4;
  const int kq4 = (tid & 7) * 4;

  int rowA[2];
  const float* aptr[2];
  const float* bptr[2];
#pragma unroll
  for (int s = 0; s < 2; ++s) {
    const int row = (tid >> 3) + 32 * s;
    rowA[s] = row;
    const int m = mtile * 64 + row;
    const float* p = nullptr;
    if (m < NT) {
      const int tt = m / 100, rem = m % 100, hh = rem / 10, ww = rem % 10;
      const int h = hi * 10 + hh, w = wi * 10 + ww;
      if (h < Hh && w < Ww)
        p = x + ((size_t)((b * Tt + tt) * NPOS + h * Ww + w)) * Cc + kq4;
    }
    aptr[s] = p;
    bptr[s] = qw + ((size_t)(ntile * 64 + row)) * Cc + kq4;
  }

  float acc[4][4] = {};

  for (int kb = 0; kb < 12; ++kb) {
    const int k0 = kb * 32;
    float4 av[2], bv[2];
#pragma unroll
    for (int s = 0; s < 2; ++s) {
      av[s] = aptr[s] ? *(const float4*)(aptr[s] + k0)
                      : make_float4(0.f, 0.f, 0.f, 0.f);
      bv[s] = *(const float4*)(bptr[s] + k0);
    }
    __syncthreads();  // previous compute done before overwrite
#pragma unroll
    for (int s = 0; s < 2; ++s) {
      As[kq4 + 0][rowA[s]] = av[s].x;
      As[kq4 + 1][rowA[s]] = av[s].y;
      As[kq4 + 2][rowA[s]] = av[s].z;
      As[kq4 + 3][rowA[s]] = av[s].w;
      Bs[kq4 + 0][rowA[s]] = bv[s].x;
      Bs[kq4 + 1][rowA[s]] = bv[s].y;
      Bs[kq4 + 2][rowA[s]] = bv[s].z;
      Bs[kq4 + 3][rowA[s]] = bv[s].w;
    }
    __syncthreads();
#pragma unroll
    for (int kk = 0; kk < 32; ++kk) {
      const float4 a4 = *(const float4*)&As[kk][ty * 4];
      const float4 b4 = *(const float4*)&Bs[kk][tx * 4];
      acc[0][0] += a4.x * b4.x; acc[0][1] += a4.x * b4.y;
      acc[0][2] += a4.x * b4.z; acc[0][3] += a4.x * b4.w;
      acc[1][0] += a4.y * b4.x; acc[1][1] += a4.y * b4.y;
      acc[1][2] += a4.y * b4.z; acc[1][3] += a4.y * b4.w;
      acc[2][0] += a4.z * b4.x; acc[2][1] += a4.z * b4.y;
      acc[2][2] += a4.z * b4.z; acc[2][3] += a4.z * b4.w;
      acc[3][0] += a4.w * b4.x; acc[3][1] += a4.w * b4.y;
      acc[3][2] += a4.w * b4.z; acc[3][3] += a4.w * b4.w;
    }
  }

  // epilogue: scatter to Q/K/V windowed [bw][head][m][hd]
  const int nb = ntile * 64 + tx * 4;   // 0..1151, 4 consecutive stay in head
  const int which = nb / Cc;            // 0=q 1=k 2=v
  const int nloc = nb - which * Cc;
  const int headi = nloc >> 5, d = nloc & 31;
  float* op = (which == 0) ? qo : (which == 1 ? ko : vo);
  const size_t obase =
      (((size_t)(b * NWIN + win) * NH + headi) * NT) * HD + d;
#pragma unroll
  for (int jm = 0; jm < 4; ++jm) {
    const int m = mtile * 64 + ty * 4 + jm;
    if (m < NT) {
      float4 st = make_float4(acc[jm][0], acc[jm][1], acc[jm][2], acc[jm][3]);
      *(float4*)(op + obase + (size_t)m * HD) = st;
    }
  }
}

// ---------------------------------------------------------------------------
// Kernel 2: per-(window,head) attention. K,V staged dense in LDS (102.4 KB,
// uniform-address broadcast reads -> conflict-free). Each lane owns 2 query
// rows fully in registers; online softmax with deferred rescale (thr=8).
// Output written directly into the cropped/un-windowed token layout.
// ---------------------------------------------------------------------------
__global__ __launch_bounds__(256) void attn_kernel(
    const float* __restrict__ qg, const float* __restrict__ kg,
    const float* __restrict__ vg, float* __restrict__ aout) {
  __shared__ float Ks[NT * HD];
  __shared__ float Vs[NT * HD];

  const int blk = blockIdx.x;  // 0..599
  const int head = blk % NH;
  const int bw = blk / NH;
  const int b = bw / NWIN, win = bw % NWIN;
  const int hi = win / 5, wi = win % 5;

  const size_t base = ((size_t)bw * NH + head) * (size_t)(NT * HD);

  {
    const float4* k4 = (const float4*)(kg + base);
    const float4* v4 = (const float4*)(vg + base);
    float4* Ks4 = (float4*)Ks;
    float4* Vs4 = (float4*)Vs;
    for (int slot = threadIdx.x; slot < NT * HD / 4; slot += 256) {
      Ks4[slot] = k4[slot];
      Vs4[slot] = v4[slot];
    }
  }
  __syncthreads();

  const int lane = threadIdx.x & 63;
  const int wid = threadIdx.x >> 6;
  const int r0 = wid * 128 + lane;
  const int r1 = r0 + 64;
  const bool in0 = r0 < NT, in1 = r1 < NT;

  float q0[HD], q1[HD];
#pragma unroll
  for (int j = 0; j < 8; ++j) {
    float4 t0 = in0 ? *(const float4*)(qg + base + (size_t)r0 * HD + j * 4)
                    : make_float4(0.f, 0.f, 0.f, 0.f);
    float4 t1 = in1 ? *(const float4*)(qg + base + (size_t)r1 * HD + j * 4)
                    : make_float4(0.f, 0.f, 0.f, 0.f);
    q0[j * 4 + 0] = t0.x * SCALE; q0[j * 4 + 1] = t0.y * SCALE;
    q0[j * 4 + 2] = t0.z * SCALE; q0[j * 4 + 3] = t0.w * SCALE;
    q1[j * 4 + 0] = t1.x * SCALE; q1[j * 4 + 1] = t1.y * SCALE;
    q1[j * 4 + 2] = t1.z * SCALE; q1[j * 4 + 3] = t1.w * SCALE;
  }

  float m0 = 0.f, l0 = 0.f, m1 = 0.f, l1 = 0.f;
  float o0[HD] = {}, o1[HD] = {};

  for (int c = 0; c < NT; ++c) {
    const float* kc = &Ks[c * HD];
    float sp0[4] = {0.f, 0.f, 0.f, 0.f};
    float sp1[4] = {0.f, 0.f, 0.f, 0.f};
#pragma unroll
    for (int j = 0; j < 8; ++j) {
      const float4 kv = *(const float4*)(kc + j * 4);
      sp0[0] += q0[j * 4 + 0] * kv.x; sp0[1] += q0[j * 4 + 1] * kv.y;
      sp0[2] += q0[j * 4 + 2] * kv.z; sp0[3] += q0[j * 4 + 3] * kv.w;
      sp1[0] += q1[j * 4 + 0] * kv.x; sp1[1] += q1[j * 4 + 1] * kv.y;
      sp1[2] += q1[j * 4 + 2] * kv.z; sp1[3] += q1[j * 4 + 3] * kv.w;
    }
    const float s0 = (sp0[0] + sp0[1]) + (sp0[2] + sp0[3]);
    const float s1 = (sp1[0] + sp1[1]) + (sp1[2] + sp1[3]);

    // deferred-rescale online softmax (rare branch; scores are O(1))
    if (s0 > m0 + 8.f) {
      const float cr = __expf(m0 - s0);
      l0 *= cr;
#pragma unroll
      for (int d = 0; d < HD; ++d) o0[d] *= cr;
      m0 = s0;
    }
    if (s1 > m1 + 8.f) {
      const float cr = __expf(m1 - s1);
      l1 *= cr;
#pragma unroll
      for (int d = 0; d < HD; ++d) o1[d] *= cr;
      m1 = s1;
    }
    const float p0 = __expf(s0 - m0);
    const float p1 = __expf(s1 - m1);
    l0 += p0;
    l1 += p1;

    const float* vc = &Vs[c * HD];
#pragma unroll
    for (int j = 0; j < 8; ++j) {
      const float4 vv = *(const float4*)(vc + j * 4);
      o0[j * 4 + 0] += p0 * vv.x; o0[j * 4 + 1] += p0 * vv.y;
      o0[j * 4 + 2] += p0 * vv.z; o0[j * 4 + 3] += p0 * vv.w;
      o1[j * 4 + 0] += p1 * vv.x; o1[j * 4 + 1] += p1 * vv.y;
      o1[j * 4 + 2] += p1 * vv.z; o1[j * 4 + 3] += p1 * vv.w;
    }
  }

  // store (crop: skip padded query rows)
  if (in0) {
    const int tt = r0 / 100, rem = r0 % 100, hh = rem / 10, ww = rem % 10;
    const int h = hi * 10 + hh, w = wi * 10 + ww;
    if (h < Hh && w < Ww) {
      float* dst =
          aout + ((size_t)((b * Tt + tt) * NPOS + h * Ww + w)) * Cc + head * HD;
      const float inv = 1.f / l0;
#pragma unroll
      for (int j = 0; j < 8; ++j) {
        float4 st = make_float4(o0[j * 4 + 0] * inv, o0[j * 4 + 1] * inv,
                                o0[j * 4 + 2] * inv, o0[j * 4 + 3] * inv);
        *(float4*)(dst + j * 4) = st;
      }
    }
  }
  if (in1) {
    const int tt = r1 / 100, rem = r1 % 100, hh = rem / 10, ww = rem % 10;
    const int h = hi * 10 + hh, w = wi * 10 + ww;
    if (h < Hh && w < Ww) {
      float* dst =
          aout + ((size_t)((b * Tt + tt) * NPOS + h * Ww + w)) * Cc + head * HD;
      const float inv = 1.f / l1;
#pragma unroll
      for (int j = 0; j < 8; ++j) {
        float4 st = make_float4(o1[j * 4 + 0] * inv, o1[j * 4 + 1] * inv,
                                o1[j * 4 + 2] * inv, o1[j * 4 + 3] * inv);
        *(float4*)(dst + j * 4) = st;
      }
    }
  }
}

// ---------------------------------------------------------------------------
// Kernel 3: output projection. (15488 x 384) @ (384 x 384)^T + bias.
// 15488 = 242*64 exactly -> no M guard.
// ---------------------------------------------------------------------------
__global__ __launch_bounds__(256) void proj_kernel(
    const float* __restrict__ a, const float* __restrict__ w,
    const float* __restrict__ bias, float* __restrict__ out) {
  __shared__ float As[32][68];
  __shared__ float Bs[32][68];

  const int ntile = blockIdx.x;  // 0..5
  const int mtile = blockIdx.y;  // 0..241
  const int tid = threadIdx.x;
  const int tx = tid & 15, ty = tid >> 4;
  const int kq4 = (tid & 7) * 4;

  int rowA[2];
  const float* aptr[2];
  const float* bptr[2];
#pragma unroll
  for (int s = 0; s < 2; ++s) {
    const int row = (tid >> 3) + 32 * s;
    rowA[s] = row;
    aptr[s] = a + ((size_t)(mtile * 64 + row)) * Cc + kq4;
    bptr[s] = w + ((size_t)(ntile * 64 + row)) * Cc + kq4;
  }

  float acc[4][4] = {};

  for (int kb = 0; kb < 12; ++kb) {
    const int k0 = kb * 32;
    float4 av[2], bv[2];
#pragma unroll
    for (int s = 0; s < 2; ++s) {
      av[s] = *(const float4*)(aptr[s] + k0);
      bv[s] = *(const float4*)(bptr[s] + k0);
    }
    __syncthreads();
#pragma unroll
    for (int s = 0; s < 2; ++s) {
      As[kq4 + 0][rowA[s]] = av[s].x;
      As[kq4 + 1][rowA[s]] = av[s].y;
      As[kq4 + 2][rowA[s]] = av[s].z;
      As[kq4 + 3][rowA[s]] = av[s].w;
      Bs[kq4 + 0][rowA[s]] = bv[s].x;
      Bs[kq4 + 1][rowA[s]] = bv[s].y;
      Bs[kq4 + 2][rowA[s]] = bv[s].z;
      Bs[kq4 + 3][rowA[s]] = bv[s].w;
    }
    __syncthreads();
#pragma unroll
    for (int kk = 0; kk < 32; ++kk) {
      const float4 a4 = *(const float4*)&As[kk][ty * 4];
      const float4 b4 = *(const float4*)&Bs[kk][tx * 4];
      acc[0][0] += a4.x * b4.x; acc[0][1] += a4.x * b4.y;
      acc[0][2] += a4.x * b4.z; acc[0][3] += a4.x * b4.w;
      acc[1][0] += a4.y * b4.x; acc[1][1] += a4.y * b4.y;
      acc[1][2] += a4.y * b4.z; acc[1][3] += a4.y * b4.w;
      acc[2][0] += a4.z * b4.x; acc[2][1] += a4.z * b4.y;
      acc[2][2] += a4.z * b4.z; acc[2][3] += a4.z * b4.w;
      acc[3][0] += a4.w * b4.x; acc[3][1] += a4.w * b4.y;
      acc[3][2] += a4.w * b4.z; acc[3][3] += a4.w * b4.w;
    }
  }

  const int nb = ntile * 64 + tx * 4;
  const float4 bb = *(const float4*)(bias + nb);
#pragma unroll
  for (int jm = 0; jm < 4; ++jm) {
    const int m = mtile * 64 + ty * 4 + jm;
    float4 st = make_float4(acc[jm][0] + bb.x, acc[jm][1] + bb.y,
                            acc[jm][2] + bb.z, acc[jm][3] + bb.w);
    *(float4*)(out + (size_t)m * Cc + nb) = st;
  }
}

// ---------------------------------------------------------------------------
extern "C" void kernel_launch(void* const* d_in, const int* in_sizes, int n_in,
                              void* d_out, int out_size, void* d_ws,
                              size_t ws_size, hipStream_t stream) {
  const float* x      = (const float*)d_in[0];
  const float* qkv_w  = (const float*)d_in[1];
  const float* proj_w = (const float*)d_in[2];
  const float* proj_b = (const float*)d_in[3];
  // d_in[4..6] = t, H, W scalars (compile-time constants here)

  float* wsf = (float*)d_ws;
  float* q    = wsf;
  float* k    = wsf + QSZ;
  float* v    = wsf + 2 * QSZ;
  float* attn = wsf + 3 * QSZ;  // [15488][384] cropped token layout
  // total ws use: (3*7,680,000 + 5,947,392)*4 B ~= 116 MB

  qkv_kernel<<<dim3(18, 7, 50), 256, 0, stream>>>(x, qkv_w, q, k, v);
  attn_kernel<<<600, 256, 0, stream>>>(q, k, v, attn);
  proj_kernel<<<dim3(6, 242), 256, 0, stream>>>(attn, proj_w, proj_b,
                                                (float*)d_out);
}

// Round 2
// 240.948 us; speedup vs baseline: 3.6105x; 3.6105x over previous
//
#include <hip/hip_runtime.h>
#include <cstddef>

typedef __attribute__((ext_vector_type(8))) short bf16x8;
typedef __attribute__((ext_vector_type(4))) float f32x4;
typedef unsigned short ushort_t;

namespace {
constexpr int Tt = 4, Hh = 44, Ww = 44, Cc = 384, NH = 12, HD = 32;
constexpr int NWIN = 25, NT = 400, NPOS = Hh * Ww;
constexpr float SCALE = 0.17677669529663687f;  // 1/sqrt(32)
constexpr size_t XN  = (size_t)2 * Tt * NPOS * Cc;  // 5,947,392
constexpr size_t WN  = (size_t)3 * Cc * Cc;         // 442,368
constexpr size_t PWN = (size_t)Cc * Cc;             // 147,456
constexpr size_t QSZ = (size_t)50 * NH * NT * HD;   // 7,680,000
}

__device__ __forceinline__ ushort_t f2bf(float f) {
  unsigned u = __builtin_bit_cast(unsigned, f);
  u += 0x7fffu + ((u >> 16) & 1u);  // RNE
  return (ushort_t)(u >> 16);
}

// ---------------------------------------------------------------------------
// K0: fp32 -> bf16 conversion (vectorized 8/thread)
// ---------------------------------------------------------------------------
__global__ __launch_bounds__(256) void conv_bf16(const float* __restrict__ s,
                                                 ushort_t* __restrict__ d,
                                                 int n8) {
  int i = blockIdx.x * 256 + threadIdx.x;
  if (i >= n8) return;
  const float4* s4 = (const float4*)s;
  float4 a = s4[2 * i], b = s4[2 * i + 1];
  union { bf16x8 v; ushort_t u[8]; } o;
  o.u[0] = f2bf(a.x); o.u[1] = f2bf(a.y); o.u[2] = f2bf(a.z); o.u[3] = f2bf(a.w);
  o.u[4] = f2bf(b.x); o.u[5] = f2bf(b.y); o.u[6] = f2bf(b.z); o.u[7] = f2bf(b.w);
  ((bf16x8*)d)[i] = o.v;
}

// ---------------------------------------------------------------------------
// K1: windowed-gather QKV GEMM, bf16 MFMA 16x16x32.
// 64x64 tile, BK=32, 4 waves x (2x2 MFMA). LDS tiles [row][k] bf16, 64B row
// pitch, XOR swizzle on 16B chunk index: s' = s ^ ((row>>1)&3)  -> conflict-
// free ds_read_b128 fragment reads. Q scaled by SCALE in epilogue.
// ---------------------------------------------------------------------------
__global__ __launch_bounds__(256) void qkv_mfma(
    const ushort_t* __restrict__ xb, const ushort_t* __restrict__ wb,
    ushort_t* __restrict__ qo, ushort_t* __restrict__ ko,
    ushort_t* __restrict__ vo) {
  __shared__ __align__(16) unsigned char As[4096];
  __shared__ __align__(16) unsigned char Bs[4096];
  const int ntile = blockIdx.x, mtile = blockIdx.y, bw = blockIdx.z;
  const int b = bw / NWIN, win = bw % NWIN, hi = win / 5, wi = win % 5;
  const int tid = threadIdx.x, lane = tid & 63, wid = tid >> 6;
  const int wm = wid >> 1, wn = wid & 1;
  const int g = lane >> 4, q = lane & 15;

  // staging: thread -> (row 0..63, 16B chunk 0..3)
  const int srow = tid >> 2, ss = tid & 3;
  const int m = mtile * 64 + srow;
  const ushort_t* ap = nullptr;
  if (m < NT) {
    int tt = m / 100, rem = m % 100, hh = rem / 10, ww2 = rem % 10;
    int h = hi * 10 + hh, w = wi * 10 + ww2;
    if (h < Hh && w < Ww)
      ap = xb + ((size_t)((b * Tt + tt) * NPOS + h * Ww + w)) * Cc + ss * 8;
  }
  const ushort_t* bp = wb + (size_t)(ntile * 64 + srow) * Cc + ss * 8;
  const int wbyte = srow * 64 + (((ss ^ (srow >> 1)) & 3) << 4);

  f32x4 acc[2][2] = {};
  for (int kb = 0; kb < 12; ++kb) {
    bf16x8 av; av[0]=0;av[1]=0;av[2]=0;av[3]=0;av[4]=0;av[5]=0;av[6]=0;av[7]=0;
    if (ap) av = *(const bf16x8*)(ap + kb * 32);
    bf16x8 bv = *(const bf16x8*)(bp + kb * 32);
    __syncthreads();
    *(bf16x8*)(As + wbyte) = av;
    *(bf16x8*)(Bs + wbyte) = bv;
    __syncthreads();
    bf16x8 afr[2], bfr[2];
#pragma unroll
    for (int i = 0; i < 2; ++i) {
      int ar = wm * 32 + i * 16 + q;
      afr[i] = *(const bf16x8*)(As + ar * 64 + (((g ^ (ar >> 1)) & 3) << 4));
      int br = wn * 32 + i * 16 + q;
      bfr[i] = *(const bf16x8*)(Bs + br * 64 + (((g ^ (br >> 1)) & 3) << 4));
    }
#pragma unroll
    for (int i = 0; i < 2; ++i)
#pragma unroll
      for (int j = 0; j < 2; ++j)
        acc[i][j] = __builtin_amdgcn_mfma_f32_16x16x32_bf16(afr[i], bfr[j],
                                                            acc[i][j], 0, 0, 0);
  }

  // epilogue: C/D frag (col = q, row = 4g+r); scatter to windowed Q/K/V bf16
  const int nq = ntile * 64 + wn * 32;
  const int which = nq / Cc;
  const int nloc = nq - which * Cc;   // multiple of 32
  const int head = nloc >> 5;
  ushort_t* op = which == 0 ? qo : (which == 1 ? ko : vo);
  const float smul = which == 0 ? SCALE : 1.0f;
  const size_t obase = ((size_t)(bw * NH + head)) * NT * HD;
#pragma unroll
  for (int i = 0; i < 2; ++i) {
#pragma unroll
    for (int r = 0; r < 4; ++r) {
      const int mrow = mtile * 64 + wm * 32 + i * 16 + 4 * g + r;
      if (mrow < NT) {
#pragma unroll
        for (int j = 0; j < 2; ++j)
          op[obase + (size_t)mrow * HD + j * 16 + q] = f2bf(acc[i][j][r] * smul);
      }
    }
  }
}

// ---------------------------------------------------------------------------
// K2: per-(window,head) attention, bf16 MFMA. 320 threads = 5 waves x 80 rows.
// K in swizzled LDS [400][32]; V transposed Vt[32][424] (848B pitch -> rows
// advance 5 mod 8 bank-groups, conflict-free B-frag reads); per-wave P buffer
// for D-layout -> A-layout relayout. Keys padded to 416 (chunks of 32);
// pad V cols zeroed, pad scores -1e30.
// ---------------------------------------------------------------------------
__global__ __launch_bounds__(320) void attn_mfma(
    const ushort_t* __restrict__ qg, const ushort_t* __restrict__ kg,
    const ushort_t* __restrict__ vg, ushort_t* __restrict__ aout) {
  __shared__ __align__(16) unsigned char Ks[25600];
  __shared__ __align__(16) unsigned char Vt[27136];
  __shared__ __align__(16) unsigned char Pb[5120];
  const int blk = blockIdx.x;
  const int head = blk % NH, bw = blk / NH;
  const int b = bw / NWIN, win = bw % NWIN, hi = win / 5, wi = win % 5;
  const size_t base = ((size_t)(bw * NH + head)) * NT * HD;
  const int tid = threadIdx.x, lane = tid & 63, wid = tid >> 6;

  // stage K (swizzled rows)
  for (int slot = tid; slot < 1600; slot += 320) {
    int row = slot >> 2, s5 = slot & 3;
    bf16x8 v = *(const bf16x8*)(kg + base + (size_t)row * HD + s5 * 8);
    *(bf16x8*)(Ks + row * 64 + (((s5 ^ (row >> 1)) & 3) << 4)) = v;
  }
  // stage V transposed (pitch 848B)
  for (int slot = tid; slot < 1600; slot += 320) {
    int key = slot >> 2, d0 = (slot & 3) * 8;
    union { bf16x8 v; ushort_t u[8]; } t;
    t.v = *(const bf16x8*)(vg + base + (size_t)key * HD + d0);
#pragma unroll
    for (int j = 0; j < 8; ++j)
      *(ushort_t*)(Vt + (d0 + j) * 848 + key * 2) = t.u[j];
  }
  // zero pad keys 400..415 (all 32 dims)
  for (int idx = tid; idx < 512; idx += 320) {
    int d = idx >> 4, kk = 400 + (idx & 15);
    *(ushort_t*)(Vt + d * 848 + kk * 2) = 0;
  }
  __syncthreads();

  const int g = lane >> 4, q = lane & 15;
  unsigned char* Pw = Pb + wid * 1024;
  const int pa_addr = q * 64 + (((g ^ (q >> 1)) & 3) << 4);

  for (int mt = 0; mt < 5; ++mt) {
    const int m0 = wid * 80 + mt * 16;
    const bf16x8 qf = *(const bf16x8*)(qg + base + (size_t)(m0 + q) * HD + g * 8);
    f32x4 o0 = {}, o1 = {};
    float mrun[4] = {-1e30f, -1e30f, -1e30f, -1e30f};
    float lrun[4] = {0.f, 0.f, 0.f, 0.f};

    for (int c = 0; c < 13; ++c) {
      const int k0r = c * 32;
      f32x4 S0, S1;
      {
        int kr = k0r + q;
        bf16x8 kf0 = *(const bf16x8*)(Ks + kr * 64 + (((g ^ (kr >> 1)) & 3) << 4));
        f32x4 z = {};
        S0 = __builtin_amdgcn_mfma_f32_16x16x32_bf16(qf, kf0, z, 0, 0, 0);
      }
      if (c < 12) {
        int kr = k0r + 16 + q;
        bf16x8 kf1 = *(const bf16x8*)(Ks + kr * 64 + (((g ^ (kr >> 1)) & 3) << 4));
        f32x4 z = {};
        S1 = __builtin_amdgcn_mfma_f32_16x16x32_bf16(qf, kf1, z, 0, 0, 0);
      } else {
        S1[0] = -1e30f; S1[1] = -1e30f; S1[2] = -1e30f; S1[3] = -1e30f;
      }

      float pv0[4], pv1[4];
#pragma unroll
      for (int r = 0; r < 4; ++r) {
        float mx = fmaxf(S0[r], S1[r]);
        mx = fmaxf(mx, __shfl_xor(mx, 1, 16));
        mx = fmaxf(mx, __shfl_xor(mx, 2, 16));
        mx = fmaxf(mx, __shfl_xor(mx, 4, 16));
        mx = fmaxf(mx, __shfl_xor(mx, 8, 16));
        float Mn = fmaxf(mrun[r], mx);
        float cf = __expf(mrun[r] - Mn);
        mrun[r] = Mn;
        float p0 = __expf(S0[r] - Mn);
        float p1 = __expf(S1[r] - Mn);
        float ps = p0 + p1;
        ps += __shfl_xor(ps, 1, 16);
        ps += __shfl_xor(ps, 2, 16);
        ps += __shfl_xor(ps, 4, 16);
        ps += __shfl_xor(ps, 8, 16);
        lrun[r] = lrun[r] * cf + ps;
        o0[r] *= cf;
        o1[r] *= cf;
        pv0[r] = p0;
        pv1[r] = p1;
      }
      // relayout P via per-wave LDS buffer (D-layout -> A-layout)
#pragma unroll
      for (int r = 0; r < 4; ++r) {
        int row = 4 * g + r;
        int sw = (row >> 1) & 3;
        int b0 = row * 64 + ((((q >> 3) ^ sw) & 3) << 4) + (q & 7) * 2;
        int b1 = row * 64 + (((((q + 16) >> 3) ^ sw) & 3) << 4) + (q & 7) * 2;
        *(ushort_t*)(Pw + b0) = f2bf(pv0[r]);
        *(ushort_t*)(Pw + b1) = f2bf(pv1[r]);
      }
      asm volatile("s_waitcnt lgkmcnt(0)" ::: "memory");
      __builtin_amdgcn_sched_barrier(0);
      bf16x8 pa  = *(const bf16x8*)(Pw + pa_addr);
      bf16x8 vf0 = *(const bf16x8*)(Vt + q * 848 + (k0r + 8 * g) * 2);
      bf16x8 vf1 = *(const bf16x8*)(Vt + (16 + q) * 848 + (k0r + 8 * g) * 2);
      o0 = __builtin_amdgcn_mfma_f32_16x16x32_bf16(pa, vf0, o0, 0, 0, 0);
      o1 = __builtin_amdgcn_mfma_f32_16x16x32_bf16(pa, vf1, o1, 0, 0, 0);
    }

    // epilogue: normalize, crop, store bf16 to token layout
#pragma unroll
    for (int r = 0; r < 4; ++r) {
      const int mrow = m0 + 4 * g + r;
      int tt = mrow / 100, rem = mrow % 100, hh = rem / 10, ww2 = rem % 10;
      int h = hi * 10 + hh, w = wi * 10 + ww2;
      if (h < Hh && w < Ww) {
        ushort_t* dst =
            aout + ((size_t)((b * Tt + tt) * NPOS + h * Ww + w)) * Cc + head * HD;
        float inv = 1.0f / lrun[r];
        dst[q]      = f2bf(o0[r] * inv);
        dst[16 + q] = f2bf(o1[r] * inv);
      }
    }
  }
}

// ---------------------------------------------------------------------------
// K3: projection GEMM (15488 x 384) @ (384 x 384)^T + bias, bf16 MFMA,
// fp32 output. Same tile structure as K1, no gather.
// ---------------------------------------------------------------------------
__global__ __launch_bounds__(256) void proj_mfma(
    const ushort_t* __restrict__ ab, const ushort_t* __restrict__ pw,
    const float* __restrict__ bias, float* __restrict__ out) {
  __shared__ __align__(16) unsigned char As[4096];
  __shared__ __align__(16) unsigned char Bs[4096];
  const int ntile = blockIdx.x, mtile = blockIdx.y;
  const int tid = threadIdx.x, lane = tid & 63, wid = tid >> 6;
  const int wm = wid >> 1, wn = wid & 1;
  const int g = lane >> 4, q = lane & 15;

  const int srow = tid >> 2, ss = tid & 3;
  const ushort_t* ap = ab + (size_t)(mtile * 64 + srow) * Cc + ss * 8;
  const ushort_t* bp = pw + (size_t)(ntile * 64 + srow) * Cc + ss * 8;
  const int wbyte = srow * 64 + (((ss ^ (srow >> 1)) & 3) << 4);

  f32x4 acc[2][2] = {};
  for (int kb = 0; kb < 12; ++kb) {
    bf16x8 av = *(const bf16x8*)(ap + kb * 32);
    bf16x8 bv = *(const bf16x8*)(bp + kb * 32);
    __syncthreads();
    *(bf16x8*)(As + wbyte) = av;
    *(bf16x8*)(Bs + wbyte) = bv;
    __syncthreads();
    bf16x8 afr[2], bfr[2];
#pragma unroll
    for (int i = 0; i < 2; ++i) {
      int ar = wm * 32 + i * 16 + q;
      afr[i] = *(const bf16x8*)(As + ar * 64 + (((g ^ (ar >> 1)) & 3) << 4));
      int br = wn * 32 + i * 16 + q;
      bfr[i] = *(const bf16x8*)(Bs + br * 64 + (((g ^ (br >> 1)) & 3) << 4));
    }
#pragma unroll
    for (int i = 0; i < 2; ++i)
#pragma unroll
      for (int j = 0; j < 2; ++j)
        acc[i][j] = __builtin_amdgcn_mfma_f32_16x16x32_bf16(afr[i], bfr[j],
                                                            acc[i][j], 0, 0, 0);
  }

  const int n0 = ntile * 64 + wn * 32;
  const float b0 = bias[n0 + q], b1 = bias[n0 + 16 + q];
#pragma unroll
  for (int i = 0; i < 2; ++i) {
#pragma unroll
    for (int r = 0; r < 4; ++r) {
      const int mrow = mtile * 64 + wm * 32 + i * 16 + 4 * g + r;
      out[(size_t)mrow * Cc + n0 + q]      = acc[i][0][r] + b0;
      out[(size_t)mrow * Cc + n0 + 16 + q] = acc[i][1][r] + b1;
    }
  }
}

// ---------------------------------------------------------------------------
extern "C" void kernel_launch(void* const* d_in, const int* in_sizes, int n_in,
                              void* d_out, int out_size, void* d_ws,
                              size_t ws_size, hipStream_t stream) {
  const float* x      = (const float*)d_in[0];
  const float* qkv_w  = (const float*)d_in[1];
  const float* proj_w = (const float*)d_in[2];
  const float* proj_b = (const float*)d_in[3];

  ushort_t* xb    = (ushort_t*)d_ws;
  ushort_t* wb    = xb + XN;
  ushort_t* pwb   = wb + WN;
  ushort_t* Q     = pwb + PWN;
  ushort_t* K     = Q + QSZ;
  ushort_t* V     = K + QSZ;
  ushort_t* attnb = V + QSZ;
  // total ~71 MB of d_ws

  conv_bf16<<<(int)(XN / 8 + 255) / 256, 256, 0, stream>>>(x, xb, (int)(XN / 8));
  conv_bf16<<<(int)(WN / 8 + 255) / 256, 256, 0, stream>>>(qkv_w, wb, (int)(WN / 8));
  conv_bf16<<<(int)(PWN / 8 + 255) / 256, 256, 0, stream>>>(proj_w, pwb, (int)(PWN / 8));

  qkv_mfma<<<dim3(18, 7, 50), 256, 0, stream>>>(xb, wb, Q, K, V);
  attn_mfma<<<600, 320, 0, stream>>>(Q, K, V, attnb);
  proj_mfma<<<dim3(6, 242), 256, 0, stream>>>(attnb, pwb, proj_b, (float*)d_out);
}

// Round 3
// 113.068 us; speedup vs baseline: 7.6940x; 2.1310x over previous
//
#include <hip/hip_runtime.h>
#include <cstddef>

typedef __attribute__((ext_vector_type(8))) short bf16x8;
typedef __attribute__((ext_vector_type(4))) float f32x4;
typedef __attribute__((ext_vector_type(16))) float f32x16;
typedef unsigned short ushort_t;

namespace {
constexpr int Tt = 4, Hh = 44, Ww = 44, Cc = 384, NH = 12, HD = 32;
constexpr int NWIN = 25, NT = 400, NPOS = Hh * Ww;
constexpr float SCALE = 0.17677669529663687f;  // 1/sqrt(32)
constexpr float LOG2E = 1.4426950408889634f;
constexpr size_t XN  = (size_t)2 * Tt * NPOS * Cc;  // 5,947,392
constexpr size_t WN  = (size_t)3 * Cc * Cc;         // 442,368
constexpr size_t PWN = (size_t)Cc * Cc;             // 147,456
constexpr size_t QSZ = (size_t)50 * NH * NT * HD;   // 7,680,000
}

__device__ __forceinline__ ushort_t f2bf(float f) {
  unsigned u = __builtin_bit_cast(unsigned, f);
  u += 0x7fffu + ((u >> 16) & 1u);  // RNE
  return (ushort_t)(u >> 16);
}

__device__ __forceinline__ unsigned cvt_pk_bf16(float a, float b) {
  unsigned r;
  asm volatile("v_cvt_pk_bf16_f32 %0, %1, %2" : "=v"(r) : "v"(a), "v"(b));
  return r;  // lo16 = bf16(a), hi16 = bf16(b)
}

// ---------------------------------------------------------------------------
// K0: fp32 -> bf16 conversion (vectorized 8/thread)
// ---------------------------------------------------------------------------
__global__ __launch_bounds__(256) void conv_bf16(const float* __restrict__ s,
                                                 ushort_t* __restrict__ d,
                                                 int n8) {
  int i = blockIdx.x * 256 + threadIdx.x;
  if (i >= n8) return;
  const float4* s4 = (const float4*)s;
  float4 a = s4[2 * i], b = s4[2 * i + 1];
  union { bf16x8 v; ushort_t u[8]; } o;
  o.u[0] = f2bf(a.x); o.u[1] = f2bf(a.y); o.u[2] = f2bf(a.z); o.u[3] = f2bf(a.w);
  o.u[4] = f2bf(b.x); o.u[5] = f2bf(b.y); o.u[6] = f2bf(b.z); o.u[7] = f2bf(b.w);
  ((bf16x8*)d)[i] = o.v;
}

// ---------------------------------------------------------------------------
// K1: windowed-gather QKV GEMM, bf16 MFMA 16x16x32 (unchanged from R2 except
// Q is pre-scaled by SCALE*LOG2E so attention can use exp2 directly).
// ---------------------------------------------------------------------------
__global__ __launch_bounds__(256) void qkv_mfma(
    const ushort_t* __restrict__ xb, const ushort_t* __restrict__ wb,
    ushort_t* __restrict__ qo, ushort_t* __restrict__ ko,
    ushort_t* __restrict__ vo) {
  __shared__ __align__(16) unsigned char As[4096];
  __shared__ __align__(16) unsigned char Bs[4096];
  const int ntile = blockIdx.x, mtile = blockIdx.y, bw = blockIdx.z;
  const int b = bw / NWIN, win = bw % NWIN, hi = win / 5, wi = win % 5;
  const int tid = threadIdx.x, lane = tid & 63, wid = tid >> 6;
  const int wm = wid >> 1, wn = wid & 1;
  const int g = lane >> 4, q = lane & 15;

  const int srow = tid >> 2, ss = tid & 3;
  const int m = mtile * 64 + srow;
  const ushort_t* ap = nullptr;
  if (m < NT) {
    int tt = m / 100, rem = m % 100, hh = rem / 10, ww2 = rem % 10;
    int h = hi * 10 + hh, w = wi * 10 + ww2;
    if (h < Hh && w < Ww)
      ap = xb + ((size_t)((b * Tt + tt) * NPOS + h * Ww + w)) * Cc + ss * 8;
  }
  const ushort_t* bp = wb + (size_t)(ntile * 64 + srow) * Cc + ss * 8;
  const int wbyte = srow * 64 + (((ss ^ (srow >> 1)) & 3) << 4);

  f32x4 acc[2][2] = {};
  for (int kb = 0; kb < 12; ++kb) {
    bf16x8 av; av[0]=0;av[1]=0;av[2]=0;av[3]=0;av[4]=0;av[5]=0;av[6]=0;av[7]=0;
    if (ap) av = *(const bf16x8*)(ap + kb * 32);
    bf16x8 bv = *(const bf16x8*)(bp + kb * 32);
    __syncthreads();
    *(bf16x8*)(As + wbyte) = av;
    *(bf16x8*)(Bs + wbyte) = bv;
    __syncthreads();
    bf16x8 afr[2], bfr[2];
#pragma unroll
    for (int i = 0; i < 2; ++i) {
      int ar = wm * 32 + i * 16 + q;
      afr[i] = *(const bf16x8*)(As + ar * 64 + (((g ^ (ar >> 1)) & 3) << 4));
      int br = wn * 32 + i * 16 + q;
      bfr[i] = *(const bf16x8*)(Bs + br * 64 + (((g ^ (br >> 1)) & 3) << 4));
    }
#pragma unroll
    for (int i = 0; i < 2; ++i)
#pragma unroll
      for (int j = 0; j < 2; ++j)
        acc[i][j] = __builtin_amdgcn_mfma_f32_16x16x32_bf16(afr[i], bfr[j],
                                                            acc[i][j], 0, 0, 0);
  }

  const int nq = ntile * 64 + wn * 32;
  const int which = nq / Cc;
  const int nloc = nq - which * Cc;
  const int head = nloc >> 5;
  ushort_t* op = which == 0 ? qo : (which == 1 ? ko : vo);
  const float smul = which == 0 ? SCALE * LOG2E : 1.0f;
  const size_t obase = ((size_t)(bw * NH + head)) * NT * HD;
#pragma unroll
  for (int i = 0; i < 2; ++i) {
#pragma unroll
    for (int r = 0; r < 4; ++r) {
      const int mrow = mtile * 64 + wm * 32 + i * 16 + 4 * g + r;
      if (mrow < NT) {
#pragma unroll
        for (int j = 0; j < 2; ++j)
          op[obase + (size_t)mrow * HD + j * 16 + q] = f2bf(acc[i][j][r] * smul);
      }
    }
  }
}

// ---------------------------------------------------------------------------
// K2: attention, swapped-QKT 32x32x16 structure (m214-style).
// Grid 1200 = 600 (window,head) x 2 query strips. 512 threads = 8 waves; each
// wave owns 32 query rows (strip1: 5 active waves cover rows 256..415).
//
// Per 32-key chunk c:
//   S^T = mfma(A=K[32 keys], B=Q[32 queries])  (2 MFMAs, K-dim = hd split 2x16)
//     D layout: col=lane&31 = query, row(reg,hi) = (reg&3)+8*(reg>>2)+4*hi = key
//   -> softmax fully in-register per query column (in-lane tree + 1 shfl_xor 32)
//   -> P^T -> bf16 B-frags via 8 cvt_pk + 4 v_permlane32_swap:
//        hi=0 lane e[0..15] = keys {0-3,8-11,16-19,24-27}; hi=1: +4
//        w0=pk(e0,e1) w1=pk(e2,e3) w2=pk(e4,e5) w3=pk(e6,e7) (sub0: keys 0-15)
//        swap(w0,w2): w0' = [w0_lo|w2_lo] -> word0 = keys(0,1)/(8,9)   OK
//                     w2' = [w0_hi|w2_hi] -> word2 = keys(4,5)/(12,13) OK
//        swap(w1,w3) -> word1/word3; frag sub0 = [w0',w1',w2',w3']; sub1: w4..w7
//   O^T = mfma(A=V^T, B=P^T) accumulates (d=32 rows = exactly M).
// V^T staged once per block in LDS, pitch 896B, XOR swizzle
//   chunk' = (key>>3) ^ (d&7) ^ ((d>>3)&3)  -> conflict-free b128 reads,
//   <=2-way staging writes. K operand read direct from global (L1-resident).
// ---------------------------------------------------------------------------
__global__ __launch_bounds__(512) void attn_mfma(
    const ushort_t* __restrict__ qg, const ushort_t* __restrict__ kg,
    const ushort_t* __restrict__ vg, ushort_t* __restrict__ aout) {
  __shared__ __align__(16) unsigned char Vt[32 * 896];

  const int blk = blockIdx.x;
  const int strip = blk & 1;
  const int wh = blk >> 1;
  const int head = wh % NH, bw = wh / NH;
  const int b = bw / NWIN, win = bw % NWIN, hi5 = win / 5, wi5 = win % 5;
  const size_t base = ((size_t)(bw * NH + head)) * (size_t)(NT * HD);

  const int tid = threadIdx.x, lane = tid & 63, wid = tid >> 6;

  // ---- stage V^T (keys 400..415 zeroed: P=0 there, but avoid NaN*0) ----
  for (int slot = tid; slot < 1664; slot += 512) {
    const int key = slot >> 2, dblk = (slot & 3) * 8;
    union { bf16x8 v; ushort_t u[8]; } t;
    if (key < NT) {
      t.v = *(const bf16x8*)(vg + base + (size_t)key * HD + dblk);
    } else {
#pragma unroll
      for (int j = 0; j < 8; ++j) t.u[j] = 0;
    }
    const int kc = key >> 3, klo = key & 7;
#pragma unroll
    for (int j = 0; j < 8; ++j) {
      const int d = dblk + j;
      const int f = (d & 7) ^ ((d >> 3) & 3);
      *(ushort_t*)(Vt + d * 896 + ((kc ^ f) << 4) + klo * 2) = t.u[j];
    }
  }
  __syncthreads();

  if (strip == 1 && wid >= 5) return;  // spare waves (after staging+barrier)

  const int l31 = lane & 31, hi = lane >> 5;
  const int qrow = strip * 256 + wid * 32 + l31;
  const int qsrc = qrow < NT ? qrow : NT - 1;

  // Q B-frags: B[col=query][k=dim 8hi..8hi+7], sub0 = dims 0-15, sub1 = 16-31
  const bf16x8 qf0 = *(const bf16x8*)(qg + base + (size_t)qsrc * HD + hi * 8);
  const bf16x8 qf1 = *(const bf16x8*)(qg + base + (size_t)qsrc * HD + 16 + hi * 8);

  // K A-frags chunk 0 (A[row=key][k=dim]), prefetched
  const ushort_t* kbase = kg + base;
  bf16x8 kf0 = *(const bf16x8*)(kbase + (size_t)l31 * HD + hi * 8);
  bf16x8 kf1 = *(const bf16x8*)(kbase + (size_t)l31 * HD + 16 + hi * 8);

  const int fv = (l31 & 7) ^ ((l31 >> 3) & 3);  // V^T read swizzle for d=l31
  const unsigned char* vrow = Vt + l31 * 896;

  f32x16 o = {};
  float mrun = -1e30f, lrun = 0.f;

  for (int c = 0; c < 13; ++c) {
    f32x16 s = {};
    s = __builtin_amdgcn_mfma_f32_32x32x16_bf16(kf0, qf0, s, 0, 0, 0);
    s = __builtin_amdgcn_mfma_f32_32x32x16_bf16(kf1, qf1, s, 0, 0, 0);

    if (c < 12) {  // prefetch next K chunk (clamped at the 416-pad tail)
      const int kr = (c == 11) ? (384 + (l31 < 15 ? l31 : 15)) : (c + 1) * 32 + l31;
      kf0 = *(const bf16x8*)(kbase + (size_t)kr * HD + hi * 8);
      kf1 = *(const bf16x8*)(kbase + (size_t)kr * HD + 16 + hi * 8);
    }

    if (c == 12) {  // keys 400..415 = rows 16..31 of chunk = regs 8..15
#pragma unroll
      for (int r = 8; r < 16; ++r) s[r] = -1e30f;
    }

    // ---- in-register softmax over this chunk's 32 keys ----
    float m01 = fmaxf(s[0], s[1]),   m23 = fmaxf(s[2], s[3]);
    float m45 = fmaxf(s[4], s[5]),   m67 = fmaxf(s[6], s[7]);
    float m89 = fmaxf(s[8], s[9]),   mab = fmaxf(s[10], s[11]);
    float mcd = fmaxf(s[12], s[13]), mef = fmaxf(s[14], s[15]);
    float mc = fmaxf(fmaxf(fmaxf(m01, m23), fmaxf(m45, m67)),
                     fmaxf(fmaxf(m89, mab), fmaxf(mcd, mef)));
    mc = fmaxf(mc, __shfl_xor(mc, 32));
    const float mnew = fmaxf(mrun, mc);
    const float cf = __builtin_amdgcn_exp2f(mrun - mnew);
    mrun = mnew;

    float e[16];
#pragma unroll
    for (int r = 0; r < 16; ++r) e[r] = __builtin_amdgcn_exp2f(s[r] - mnew);
    float ps = ((e[0] + e[1]) + (e[2] + e[3])) + ((e[4] + e[5]) + (e[6] + e[7])) +
               (((e[8] + e[9]) + (e[10] + e[11])) + ((e[12] + e[13]) + (e[14] + e[15])));
    ps += __shfl_xor(ps, 32);
    lrun = lrun * cf + ps;
#pragma unroll
    for (int r = 0; r < 16; ++r) o[r] *= cf;

    // ---- P^T -> bf16 B-frags (cvt_pk + permlane32_swap) ----
    unsigned w0 = cvt_pk_bf16(e[0], e[1]),   w1 = cvt_pk_bf16(e[2], e[3]);
    unsigned w2 = cvt_pk_bf16(e[4], e[5]),   w3 = cvt_pk_bf16(e[6], e[7]);
    unsigned w4 = cvt_pk_bf16(e[8], e[9]),   w5 = cvt_pk_bf16(e[10], e[11]);
    unsigned w6 = cvt_pk_bf16(e[12], e[13]), w7 = cvt_pk_bf16(e[14], e[15]);
    asm volatile("v_permlane32_swap_b32 %0, %1" : "+v"(w0), "+v"(w2));
    asm volatile("v_permlane32_swap_b32 %0, %1" : "+v"(w1), "+v"(w3));
    asm volatile("v_permlane32_swap_b32 %0, %1" : "+v"(w4), "+v"(w6));
    asm volatile("v_permlane32_swap_b32 %0, %1" : "+v"(w5), "+v"(w7));
    union { bf16x8 v; unsigned u[4]; } p0, p1;
    p0.u[0] = w0; p0.u[1] = w1; p0.u[2] = w2; p0.u[3] = w3;
    p1.u[0] = w4; p1.u[1] = w5; p1.u[2] = w6; p1.u[3] = w7;

    // ---- PV: O^T += V^T @ P^T ----
    const bf16x8 vf0 = *(const bf16x8*)(vrow + (((4 * c + hi) ^ fv) << 4));
    const bf16x8 vf1 = *(const bf16x8*)(vrow + (((4 * c + 2 + hi) ^ fv) << 4));
    o = __builtin_amdgcn_mfma_f32_32x32x16_bf16(vf0, p0.v, o, 0, 0, 0);
    o = __builtin_amdgcn_mfma_f32_32x32x16_bf16(vf1, p1.v, o, 0, 0, 0);
  }

  // ---- epilogue: normalize, crop, store bf16 ----
  if (qrow < NT) {
    const int tt = qrow / 100, rem = qrow % 100, hh = rem / 10, ww2 = rem % 10;
    const int h = hi5 * 10 + hh, w = wi5 * 10 + ww2;
    if (h < Hh && w < Ww) {
      ushort_t* dst =
          aout + ((size_t)((b * Tt + tt) * NPOS + h * Ww + w)) * Cc + head * HD;
      const float inv = 1.0f / lrun;
#pragma unroll
      for (int g4 = 0; g4 < 4; ++g4) {  // regs 4g4+0..3 -> d = 8*g4 + 4*hi + 0..3
        unsigned lo = cvt_pk_bf16(o[4 * g4 + 0] * inv, o[4 * g4 + 1] * inv);
        unsigned hi2 = cvt_pk_bf16(o[4 * g4 + 2] * inv, o[4 * g4 + 3] * inv);
        uint2 st; st.x = lo; st.y = hi2;
        *(uint2*)(dst + 8 * g4 + 4 * hi) = st;
      }
    }
  }
}

// ---------------------------------------------------------------------------
// K3: projection GEMM (15488 x 384) @ (384 x 384)^T + bias, bf16 MFMA,
// fp32 output.
// ---------------------------------------------------------------------------
__global__ __launch_bounds__(256) void proj_mfma(
    const ushort_t* __restrict__ ab, const ushort_t* __restrict__ pw,
    const float* __restrict__ bias, float* __restrict__ out) {
  __shared__ __align__(16) unsigned char As[4096];
  __shared__ __align__(16) unsigned char Bs[4096];
  const int ntile = blockIdx.x, mtile = blockIdx.y;
  const int tid = threadIdx.x, lane = tid & 63, wid = tid >> 6;
  const int wm = wid >> 1, wn = wid & 1;
  const int g = lane >> 4, q = lane & 15;

  const int srow = tid >> 2, ss = tid & 3;
  const ushort_t* ap = ab + (size_t)(mtile * 64 + srow) * Cc + ss * 8;
  const ushort_t* bp = pw + (size_t)(ntile * 64 + srow) * Cc + ss * 8;
  const int wbyte = srow * 64 + (((ss ^ (srow >> 1)) & 3) << 4);

  f32x4 acc[2][2] = {};
  for (int kb = 0; kb < 12; ++kb) {
    bf16x8 av = *(const bf16x8*)(ap + kb * 32);
    bf16x8 bv = *(const bf16x8*)(bp + kb * 32);
    __syncthreads();
    *(bf16x8*)(As + wbyte) = av;
    *(bf16x8*)(Bs + wbyte) = bv;
    __syncthreads();
    bf16x8 afr[2], bfr[2];
#pragma unroll
    for (int i = 0; i < 2; ++i) {
      int ar = wm * 32 + i * 16 + q;
      afr[i] = *(const bf16x8*)(As + ar * 64 + (((g ^ (ar >> 1)) & 3) << 4));
      int br = wn * 32 + i * 16 + q;
      bfr[i] = *(const bf16x8*)(Bs + br * 64 + (((g ^ (br >> 1)) & 3) << 4));
    }
#pragma unroll
    for (int i = 0; i < 2; ++i)
#pragma unroll
      for (int j = 0; j < 2; ++j)
        acc[i][j] = __builtin_amdgcn_mfma_f32_16x16x32_bf16(afr[i], bfr[j],
                                                            acc[i][j], 0, 0, 0);
  }

  const int n0 = ntile * 64 + wn * 32;
  const float b0 = bias[n0 + q], b1 = bias[n0 + 16 + q];
#pragma unroll
  for (int i = 0; i < 2; ++i) {
#pragma unroll
    for (int r = 0; r < 4; ++r) {
      const int mrow = mtile * 64 + wm * 32 + i * 16 + 4 * g + r;
      out[(size_t)mrow * Cc + n0 + q]      = acc[i][0][r] + b0;
      out[(size_t)mrow * Cc + n0 + 16 + q] = acc[i][1][r] + b1;
    }
  }
}

// ---------------------------------------------------------------------------
extern "C" void kernel_launch(void* const* d_in, const int* in_sizes, int n_in,
                              void* d_out, int out_size, void* d_ws,
                              size_t ws_size, hipStream_t stream) {
  const float* x      = (const float*)d_in[0];
  const float* qkv_w  = (const float*)d_in[1];
  const float* proj_w = (const float*)d_in[2];
  const float* proj_b = (const float*)d_in[3];

  ushort_t* xb    = (ushort_t*)d_ws;
  ushort_t* wb    = xb + XN;
  ushort_t* pwb   = wb + WN;
  ushort_t* Q     = pwb + PWN;
  ushort_t* K     = Q + QSZ;
  ushort_t* V     = K + QSZ;
  ushort_t* attnb = V + QSZ;

  conv_bf16<<<(int)(XN / 8 + 255) / 256, 256, 0, stream>>>(x, xb, (int)(XN / 8));
  conv_bf16<<<(int)(WN / 8 + 255) / 256, 256, 0, stream>>>(qkv_w, wb, (int)(WN / 8));
  conv_bf16<<<(int)(PWN / 8 + 255) / 256, 256, 0, stream>>>(proj_w, pwb, (int)(PWN / 8));

  qkv_mfma<<<dim3(18, 7, 50), 256, 0, stream>>>(xb, wb, Q, K, V);
  attn_mfma<<<1200, 512, 0, stream>>>(Q, K, V, attnb);
  proj_mfma<<<dim3(6, 242), 256, 0, stream>>>(attnb, pwb, proj_b, (float*)d_out);
}

// Round 4
// 99.997 us; speedup vs baseline: 8.6997x; 1.1307x over previous
//
#include <hip/hip_runtime.h>
#include <cstddef>

typedef __attribute__((ext_vector_type(8))) short bf16x8;
typedef __attribute__((ext_vector_type(4))) float f32x4;
typedef __attribute__((ext_vector_type(16))) float f32x16;
typedef unsigned short ushort_t;

namespace {
constexpr int Tt = 4, Hh = 44, Ww = 44, Cc = 384, NH = 12, HD = 32;
constexpr int NWIN = 25, NT = 400, NPOS = Hh * Ww;
constexpr int NTOK = 2 * Tt * NPOS;                 // 15488 = 121*128
constexpr float SCALE = 0.17677669529663687f;       // 1/sqrt(32)
constexpr float LOG2E = 1.4426950408889634f;
constexpr size_t XN  = (size_t)NTOK * Cc;           // 5,947,392
constexpr size_t WN  = (size_t)3 * Cc * Cc;         // 442,368
constexpr size_t PWN = (size_t)Cc * Cc;             // 147,456
constexpr size_t QKVN = (size_t)NTOK * 3 * Cc;      // 17,842,176
}

__device__ __forceinline__ ushort_t f2bf(float f) {
  unsigned u = __builtin_bit_cast(unsigned, f);
  u += 0x7fffu + ((u >> 16) & 1u);  // RNE
  return (ushort_t)(u >> 16);
}

__device__ __forceinline__ unsigned cvt_pk_bf16(float a, float b) {
  unsigned r;
  asm volatile("v_cvt_pk_bf16_f32 %0, %1, %2" : "=v"(r) : "v"(a), "v"(b));
  return r;  // lo16 = bf16(a), hi16 = bf16(b)
}

__device__ __forceinline__ bf16x8 bf8zero() {
  bf16x8 v;
  v[0] = 0; v[1] = 0; v[2] = 0; v[3] = 0;
  v[4] = 0; v[5] = 0; v[6] = 0; v[7] = 0;
  return v;
}

// async global->LDS, 16B per lane; LDS dest = wave-uniform base + lane*16
__device__ __forceinline__ void gload16(const void* g, void* l) {
  __builtin_amdgcn_global_load_lds(
      (const __attribute__((address_space(1))) unsigned int*)g,
      (__attribute__((address_space(3))) unsigned int*)l, 16, 0, 0);
}

// window-relative index (0..415) -> token index + validity.
// Invalid (beyond NT, or padded h/w) == zero Q/K/V row in the reference.
__device__ __forceinline__ bool win_tok(int kk, int b, int hi5, int wi5,
                                        int& tok) {
  const int tt = kk / 100, rem = kk - tt * 100;
  const int hh = rem / 10, ww2 = rem - hh * 10;
  const int h = hi5 * 10 + hh, w = wi5 * 10 + ww2;
  tok = (b * Tt + tt) * NPOS + h * Ww + w;
  return (kk < NT) && (h < Hh) && (w < Ww);
}

// ---------------------------------------------------------------------------
// K0: one-launch fp32 -> bf16 conversion of x, qkv_w, proj_w.
// ---------------------------------------------------------------------------
__global__ __launch_bounds__(256) void conv_all(
    const float* __restrict__ x, const float* __restrict__ w1,
    const float* __restrict__ w2, ushort_t* __restrict__ xo,
    ushort_t* __restrict__ w1o, ushort_t* __restrict__ w2o) {
  constexpr int XN8 = (int)(XN / 8), WN8 = (int)(WN / 8), PN8 = (int)(PWN / 8);
  int i = blockIdx.x * 256 + threadIdx.x;
  if (i >= XN8 + WN8 + PN8) return;
  const float* s;
  ushort_t* d;
  int j;
  if (i < XN8)            { s = x;  d = xo;  j = i; }
  else if (i < XN8 + WN8) { s = w1; d = w1o; j = i - XN8; }
  else                    { s = w2; d = w2o; j = i - XN8 - WN8; }
  const float4* s4 = (const float4*)s;
  float4 a = s4[2 * j], bq = s4[2 * j + 1];
  union { bf16x8 v; ushort_t u[8]; } o;
  o.u[0] = f2bf(a.x);  o.u[1] = f2bf(a.y);  o.u[2] = f2bf(a.z);  o.u[3] = f2bf(a.w);
  o.u[4] = f2bf(bq.x); o.u[5] = f2bf(bq.y); o.u[6] = f2bf(bq.z); o.u[7] = f2bf(bq.w);
  ((bf16x8*)d)[j] = o.v;
}

// ---------------------------------------------------------------------------
// K1: dense QKV GEMM (no gather): [15488 x 384] @ [384 x 1152]^T -> bf16
// [token][1152] (cols 0-383=Q prescaled by SCALE*LOG2E, 384-767=K, 768+=V).
// m97 structure: 128x128 tile, BK=32, 256 thr / 2x2 waves / 64x64 per wave,
// global_load_lds(16B) with pre-swizzled source chunk g^=(row>>1)&3 (linear
// LDS dest, involution on read) -> 2-way (free) frag-read banking.
// M=121*128, N=9*128, K=12*32: fully guard-free.
// ---------------------------------------------------------------------------
__global__ __launch_bounds__(256) void qkv_mfma(
    const ushort_t* __restrict__ xb, const ushort_t* __restrict__ wb,
    ushort_t* __restrict__ qkvb) {
  __shared__ __align__(16) unsigned char As[8192];
  __shared__ __align__(16) unsigned char Bs[8192];
  const int nt = blockIdx.x, mt = blockIdx.y;
  const int tid = threadIdx.x, lane = tid & 63, wid = tid >> 6;
  const int wm = wid >> 1, wn = wid & 1;
  const int g = lane >> 4, q = lane & 15;
  const int m0 = mt * 128, n0 = nt * 128;

  const unsigned char* xB = (const unsigned char*)xb;
  const unsigned char* wB = (const unsigned char*)wb;

  size_t aoff[2], boff[2];
  unsigned ldsoff[2];
#pragma unroll
  for (int p = 0; p < 2; ++p) {
    const int row = wid * 32 + p * 16 + (lane >> 2);
    const int gs = (lane & 3) ^ ((row >> 1) & 3);
    aoff[p] = (size_t)(m0 + row) * 768 + gs * 16;  // 768 B = 384 bf16 row
    boff[p] = (size_t)(n0 + row) * 768 + gs * 16;
    ldsoff[p] = wid * 2048 + p * 1024;
  }

  f32x4 acc[4][4] = {};

  for (int kb = 0; kb < 12; ++kb) {
    if (kb) __syncthreads();
#pragma unroll
    for (int p = 0; p < 2; ++p) {
      gload16(xB + aoff[p] + kb * 64, As + ldsoff[p]);
      gload16(wB + boff[p] + kb * 64, Bs + ldsoff[p]);
    }
    __syncthreads();  // compiler drains vmcnt before barrier
    bf16x8 afr[4], bfr[4];
#pragma unroll
    for (int i = 0; i < 4; ++i) {
      const int ar = wm * 64 + i * 16 + q;
      afr[i] = *(const bf16x8*)(As + ar * 64 + ((g ^ ((ar >> 1) & 3)) << 4));
      const int br = wn * 64 + i * 16 + q;
      bfr[i] = *(const bf16x8*)(Bs + br * 64 + ((g ^ ((br >> 1) & 3)) << 4));
    }
#pragma unroll
    for (int i = 0; i < 4; ++i)
#pragma unroll
      for (int j = 0; j < 4; ++j)
        acc[i][j] = __builtin_amdgcn_mfma_f32_16x16x32_bf16(afr[i], bfr[j],
                                                            acc[i][j], 0, 0, 0);
  }

  const float QS = SCALE * LOG2E;
#pragma unroll
  for (int j = 0; j < 4; ++j) {
    const int col = n0 + wn * 64 + j * 16 + q;
    const float scl = (col < Cc) ? QS : 1.0f;
#pragma unroll
    for (int i = 0; i < 4; ++i) {
      const int rbase = m0 + wm * 64 + i * 16 + 4 * g;
#pragma unroll
      for (int r = 0; r < 4; ++r)
        qkvb[(size_t)(rbase + r) * 1152 + col] = f2bf(acc[i][j][r] * scl);
    }
  }
}

// ---------------------------------------------------------------------------
// K2: attention (R3 swapped-QKT structure), now gathering Q/K/V from the
// dense token-major qkvb by computed token address. Invalid (padded) rows
// load zeros -> identical math to R3's zero-filled windowed buffers.
// ---------------------------------------------------------------------------
__global__ __launch_bounds__(512) void attn_mfma(
    const ushort_t* __restrict__ qkvb, ushort_t* __restrict__ aout) {
  __shared__ __align__(16) unsigned char Vt[32 * 896];

  const int blk = blockIdx.x;
  const int strip = blk & 1;
  const int wh = blk >> 1;
  const int head = wh % NH, bw = wh / NH;
  const int b = bw / NWIN, win = bw % NWIN, hi5 = win / 5, wi5 = win % 5;
  const int hoff = head * HD;

  const int tid = threadIdx.x, lane = tid & 63, wid = tid >> 6;

  // ---- stage V^T gathered (invalid keys -> zeros) ----
  for (int slot = tid; slot < 1664; slot += 512) {
    const int key = slot >> 2, dblk = (slot & 3) * 8;
    int tok;
    union { bf16x8 v; ushort_t u[8]; } t;
    if (win_tok(key, b, hi5, wi5, tok)) {
      t.v = *(const bf16x8*)(qkvb + (size_t)tok * 1152 + 768 + hoff + dblk);
    } else {
      t.v = bf8zero();
    }
    const int kc = key >> 3, klo = key & 7;
#pragma unroll
    for (int j = 0; j < 8; ++j) {
      const int d = dblk + j;
      const int f = (d & 7) ^ ((d >> 3) & 3);
      *(ushort_t*)(Vt + d * 896 + ((kc ^ f) << 4) + klo * 2) = t.u[j];
    }
  }
  __syncthreads();

  if (strip == 1 && wid >= 5) return;  // rows 256..415 need only 5 waves

  const int l31 = lane & 31, hi = lane >> 5;
  const int qrow = strip * 256 + wid * 32 + l31;
  int qtok;
  const bool qv = win_tok(qrow, b, hi5, wi5, qtok);
  const int qsrc = qv ? qtok : 0;

  // Q B-frags (pre-scaled by SCALE*LOG2E in K1)
  const ushort_t* qp = qkvb + (size_t)qsrc * 1152 + hoff;
  const bf16x8 qf0 = *(const bf16x8*)(qp);
  const bf16x8 qf1 = *(const bf16x8*)(qp + 16);
  const bf16x8 qfa = *(const bf16x8*)(qp + hi * 8);        // dims 8hi..8hi+7
  const bf16x8 qfb = *(const bf16x8*)(qp + 16 + hi * 8);   // dims 16+8hi..
  (void)qf0; (void)qf1;

  // K A-frags chunk 0, prefetched (gathered, zeros if invalid)
  bf16x8 kf0, kf1;
  {
    int tok;
    if (win_tok(l31, b, hi5, wi5, tok)) {
      const ushort_t* kp = qkvb + (size_t)tok * 1152 + 384 + hoff;
      kf0 = *(const bf16x8*)(kp + hi * 8);
      kf1 = *(const bf16x8*)(kp + 16 + hi * 8);
    } else {
      kf0 = bf8zero();
      kf1 = bf8zero();
    }
  }

  const int fv = (l31 & 7) ^ ((l31 >> 3) & 3);  // V^T read swizzle for d=l31
  const unsigned char* vrow = Vt + l31 * 896;

  f32x16 o = {};
  float mrun = -1e30f, lrun = 0.f;

  for (int c = 0; c < 13; ++c) {
    f32x16 s = {};
    s = __builtin_amdgcn_mfma_f32_32x32x16_bf16(kf0, qfa, s, 0, 0, 0);
    s = __builtin_amdgcn_mfma_f32_32x32x16_bf16(kf1, qfb, s, 0, 0, 0);

    if (c < 12) {  // prefetch next K chunk
      int tok;
      if (win_tok((c + 1) * 32 + l31, b, hi5, wi5, tok)) {
        const ushort_t* kp = qkvb + (size_t)tok * 1152 + 384 + hoff;
        kf0 = *(const bf16x8*)(kp + hi * 8);
        kf1 = *(const bf16x8*)(kp + 16 + hi * 8);
      } else {
        kf0 = bf8zero();
        kf1 = bf8zero();
      }
    }

    if (c == 12) {  // keys 400..415 don't exist -> mask (rows 16..31 = regs 8..15)
#pragma unroll
      for (int r = 8; r < 16; ++r) s[r] = -1e30f;
    }

    // ---- in-register softmax over this chunk's 32 keys ----
    float m01 = fmaxf(s[0], s[1]),   m23 = fmaxf(s[2], s[3]);
    float m45 = fmaxf(s[4], s[5]),   m67 = fmaxf(s[6], s[7]);
    float m89 = fmaxf(s[8], s[9]),   mab = fmaxf(s[10], s[11]);
    float mcd = fmaxf(s[12], s[13]), mef = fmaxf(s[14], s[15]);
    float mc = fmaxf(fmaxf(fmaxf(m01, m23), fmaxf(m45, m67)),
                     fmaxf(fmaxf(m89, mab), fmaxf(mcd, mef)));
    mc = fmaxf(mc, __shfl_xor(mc, 32));
    const float mnew = fmaxf(mrun, mc);
    const float cf = __builtin_amdgcn_exp2f(mrun - mnew);
    mrun = mnew;

    float e[16];
#pragma unroll
    for (int r = 0; r < 16; ++r) e[r] = __builtin_amdgcn_exp2f(s[r] - mnew);
    float ps = ((e[0] + e[1]) + (e[2] + e[3])) + ((e[4] + e[5]) + (e[6] + e[7])) +
               (((e[8] + e[9]) + (e[10] + e[11])) +
                ((e[12] + e[13]) + (e[14] + e[15])));
    ps += __shfl_xor(ps, 32);
    lrun = lrun * cf + ps;
#pragma unroll
    for (int r = 0; r < 16; ++r) o[r] *= cf;

    // ---- P^T -> bf16 B-frags (cvt_pk + permlane32_swap) ----
    unsigned w0 = cvt_pk_bf16(e[0], e[1]),   w1 = cvt_pk_bf16(e[2], e[3]);
    unsigned w2 = cvt_pk_bf16(e[4], e[5]),   w3 = cvt_pk_bf16(e[6], e[7]);
    unsigned w4 = cvt_pk_bf16(e[8], e[9]),   w5 = cvt_pk_bf16(e[10], e[11]);
    unsigned w6 = cvt_pk_bf16(e[12], e[13]), w7 = cvt_pk_bf16(e[14], e[15]);
    asm volatile("v_permlane32_swap_b32 %0, %1" : "+v"(w0), "+v"(w2));
    asm volatile("v_permlane32_swap_b32 %0, %1" : "+v"(w1), "+v"(w3));
    asm volatile("v_permlane32_swap_b32 %0, %1" : "+v"(w4), "+v"(w6));
    asm volatile("v_permlane32_swap_b32 %0, %1" : "+v"(w5), "+v"(w7));
    union { bf16x8 v; unsigned u[4]; } p0, p1;
    p0.u[0] = w0; p0.u[1] = w1; p0.u[2] = w2; p0.u[3] = w3;
    p1.u[0] = w4; p1.u[1] = w5; p1.u[2] = w6; p1.u[3] = w7;

    // ---- PV: O^T += V^T @ P^T ----
    const bf16x8 vf0 = *(const bf16x8*)(vrow + (((4 * c + hi) ^ fv) << 4));
    const bf16x8 vf1 = *(const bf16x8*)(vrow + (((4 * c + 2 + hi) ^ fv) << 4));
    o = __builtin_amdgcn_mfma_f32_32x32x16_bf16(vf0, p0.v, o, 0, 0, 0);
    o = __builtin_amdgcn_mfma_f32_32x32x16_bf16(vf1, p1.v, o, 0, 0, 0);
  }

  // ---- epilogue: normalize, store bf16 to [token][384] ----
  if (qv) {
    ushort_t* dst = aout + (size_t)qtok * Cc + hoff;
    const float inv = 1.0f / lrun;
#pragma unroll
    for (int g4 = 0; g4 < 4; ++g4) {  // regs 4g4+0..3 -> d = 8*g4 + 4*hi + 0..3
      unsigned lo  = cvt_pk_bf16(o[4 * g4 + 0] * inv, o[4 * g4 + 1] * inv);
      unsigned hi2 = cvt_pk_bf16(o[4 * g4 + 2] * inv, o[4 * g4 + 3] * inv);
      uint2 st; st.x = lo; st.y = hi2;
      *(uint2*)(dst + 8 * g4 + 4 * hi) = st;
    }
  }
}

// ---------------------------------------------------------------------------
// K3: projection GEMM [15488 x 384] @ [384 x 384]^T + bias -> fp32 out.
// Same m97 structure as K1 (N = 3*128).
// ---------------------------------------------------------------------------
__global__ __launch_bounds__(256) void proj_mfma(
    const ushort_t* __restrict__ ab, const ushort_t* __restrict__ pw,
    const float* __restrict__ bias, float* __restrict__ out) {
  __shared__ __align__(16) unsigned char As[8192];
  __shared__ __align__(16) unsigned char Bs[8192];
  const int nt = blockIdx.x, mt = blockIdx.y;
  const int tid = threadIdx.x, lane = tid & 63, wid = tid >> 6;
  const int wm = wid >> 1, wn = wid & 1;
  const int g = lane >> 4, q = lane & 15;
  const int m0 = mt * 128, n0 = nt * 128;

  const unsigned char* aB = (const unsigned char*)ab;
  const unsigned char* wB = (const unsigned char*)pw;

  size_t aoff[2], boff[2];
  unsigned ldsoff[2];
#pragma unroll
  for (int p = 0; p < 2; ++p) {
    const int row = wid * 32 + p * 16 + (lane >> 2);
    const int gs = (lane & 3) ^ ((row >> 1) & 3);
    aoff[p] = (size_t)(m0 + row) * 768 + gs * 16;
    boff[p] = (size_t)(n0 + row) * 768 + gs * 16;
    ldsoff[p] = wid * 2048 + p * 1024;
  }

  f32x4 acc[4][4] = {};

  for (int kb = 0; kb < 12; ++kb) {
    if (kb) __syncthreads();
#pragma unroll
    for (int p = 0; p < 2; ++p) {
      gload16(aB + aoff[p] + kb * 64, As + ldsoff[p]);
      gload16(wB + boff[p] + kb * 64, Bs + ldsoff[p]);
    }
    __syncthreads();
    bf16x8 afr[4], bfr[4];
#pragma unroll
    for (int i = 0; i < 4; ++i) {
      const int ar = wm * 64 + i * 16 + q;
      afr[i] = *(const bf16x8*)(As + ar * 64 + ((g ^ ((ar >> 1) & 3)) << 4));
      const int br = wn * 64 + i * 16 + q;
      bfr[i] = *(const bf16x8*)(Bs + br * 64 + ((g ^ ((br >> 1) & 3)) << 4));
    }
#pragma unroll
    for (int i = 0; i < 4; ++i)
#pragma unroll
      for (int j = 0; j < 4; ++j)
        acc[i][j] = __builtin_amdgcn_mfma_f32_16x16x32_bf16(afr[i], bfr[j],
                                                            acc[i][j], 0, 0, 0);
  }

#pragma unroll
  for (int j = 0; j < 4; ++j) {
    const int col = n0 + wn * 64 + j * 16 + q;
    const float bj = bias[col];
#pragma unroll
    for (int i = 0; i < 4; ++i) {
      const int rbase = m0 + wm * 64 + i * 16 + 4 * g;
#pragma unroll
      for (int r = 0; r < 4; ++r)
        out[(size_t)(rbase + r) * Cc + col] = acc[i][j][r] + bj;
    }
  }
}

// ---------------------------------------------------------------------------
extern "C" void kernel_launch(void* const* d_in, const int* in_sizes, int n_in,
                              void* d_out, int out_size, void* d_ws,
                              size_t ws_size, hipStream_t stream) {
  const float* x      = (const float*)d_in[0];
  const float* qkv_w  = (const float*)d_in[1];
  const float* proj_w = (const float*)d_in[2];
  const float* proj_b = (const float*)d_in[3];

  ushort_t* xb    = (ushort_t*)d_ws;      // [15488][384] bf16
  ushort_t* wb    = xb + XN;              // [1152][384] bf16
  ushort_t* pwb   = wb + WN;              // [384][384] bf16
  ushort_t* qkvb  = pwb + PWN;            // [15488][1152] bf16
  ushort_t* attnb = qkvb + QKVN;          // [15488][384] bf16
  // total ~61 MB of d_ws

  constexpr int TOT8 = (int)((XN + WN + PWN) / 8);
  conv_all<<<(TOT8 + 255) / 256, 256, 0, stream>>>(x, qkv_w, proj_w, xb, wb, pwb);
  qkv_mfma<<<dim3(9, 121), 256, 0, stream>>>(xb, wb, qkvb);
  attn_mfma<<<1200, 512, 0, stream>>>(qkvb, attnb);
  proj_mfma<<<dim3(3, 121), 256, 0, stream>>>(attnb, pwb, proj_b, (float*)d_out);
}